// Round 25
// baseline (79.648 us; speedup 1.0000x reference)
//
#include <hip/hip_runtime.h>
#include <cmath>

// x,y: (16,3,512,512) f32. Fused separable-Gaussian SSIM, scalar mean output.
// R22 champion (sum/diff 4-field basis, 32KB LDS, row sharing + prefetch,
// XOR bank swizzle, XCD swizzle, rcp, parallel finalize) + 2 BANDS PER BLOCK:
// after the last register use of the row window (vconv q1), the next band's
// 14-row prologue is issued into the SAME registers (WAR-safe, in-order
// issue) and flies under hpass(q1) -> half the cold prologues per CU,
// plus L1 reuse of the 10 shared halo rows between consecutive bands.
constexpr int IMG_H = 512;
constexpr int IMG_W = 512;
constexpr int PLANES = 48;
constexpr int R_PER_BAND = 8;            // rows per band (2 quads)
constexpr int BPAIRS = IMG_H / 16;       // 32 band-pairs per plane
constexpr int PSTR = 512;                // field-row dwords; col c at dword c
constexpr int NSLOT = 64;                // global accumulator slots (64B apart)
constexpr int NBLK = PLANES * BPAIRS;    // 1536 (divisible by 8 XCDs)
constexpr long long TOTAL_PIX = (long long)PLANES * IMG_H * IMG_W;

struct GWin { float g[11]; };

// XOR bank swizzle on within-field-row dword offset (bits 2..4 ^= bits 5..7).
__device__ __forceinline__ int swzd(int d) { return d ^ (((d >> 5) & 7) << 2); }
__device__ __forceinline__ int swzd4(int b) { return b ^ ((b >> 3) & 7); }

template<bool CHK>
__device__ __forceinline__ float2 ld2(const float* __restrict__ base, int gr, int c0) {
    if (CHK && (unsigned)gr >= (unsigned)IMG_H) return make_float2(0.f, 0.f);
    return *(const float2*)(base + (size_t)gr * IMG_W + c0);
}

// horizontal 11-tap conv + SSIM over one LDS row (4 fields), 8 cols per lane.
__device__ __forceinline__ float hpass8(const float* __restrict__ fr0,
                                        int l, const int (&pb)[6],
                                        const GWin& win) {
    float m[4][8];
#pragma unroll
    for (int f = 0; f < 4; ++f) {
        const float* fr = fr0 + f * PSTR;
        float w24[24];
#pragma unroll
        for (int B = 0; B < 6; ++B) {
            const float4 v = *(const float4*)&fr[pb[B]];
            w24[4 * B + 0] = v.x;  w24[4 * B + 1] = v.y;
            w24[4 * B + 2] = v.z;  w24[4 * B + 3] = v.w;
        }
        if (l == 0)  { w24[3] = w24[4] = w24[5] = w24[6] = w24[7] = 0.f; }
        if (l == 63) { w24[16] = w24[17] = w24[18] = w24[19] = w24[20] = 0.f; }
        // output col c = 8l+j: window cols c-5..c+5 -> w24[j+3+k]
#pragma unroll
        for (int j = 0; j < 8; ++j) {
            float s = 0.f;
#pragma unroll
            for (int k = 0; k < 11; ++k) s += win.g[k] * w24[j + 3 + k];
            m[f][j] = s;
        }
    }
    float ls = 0.f;
#pragma unroll
    for (int u = 0; u < 8; ++u) {
        const float sb  = m[0][u];        // conv(x+y)
        const float db  = m[1][u];        // conv(x-y)
        const float css = m[2][u];        // conv((x+y)^2)
        const float cdd = m[3][u];        // conv((x-y)^2)
        const float A = sb * sb;
        const float B = db * db;
        const float C1 = 0.01f * 0.01f;
        const float C2 = 0.03f * 0.03f;
        const float n1 = 0.5f * (A - B) + C1;
        const float n2 = 0.5f * ((css - cdd) - (A - B)) + C2;
        const float d1 = 0.5f * (A + B) + C1;
        const float d2 = 0.5f * ((css + cdd) - (A + B)) + C2;
        ls += (n1 * n2) * __builtin_amdgcn_rcpf(d1 * d2 + 1e-8f);  // ~1 ulp
    }
    return ls;
}

// v-conv of 4 rows x 4 fields {s,d,ss,dd} from 14 resident register rows
template<int I0>
__device__ __forceinline__ void vconv4(const float2 (&xr)[18], const float2 (&yr)[18],
                                       float* __restrict__ hb, int pws,
                                       const GWin& win) {
    float2 acc[4][4];
#pragma unroll
    for (int j = 0; j < 4; ++j)
#pragma unroll
        for (int f = 0; f < 4; ++f) acc[j][f] = make_float2(0.f, 0.f);
#pragma unroll
    for (int k = 0; k < 14; ++k) {
        const float2 xv = xr[I0 + k], yv = yr[I0 + k];
        const float2 sv = make_float2(xv.x + yv.x, xv.y + yv.y);
        const float2 dv = make_float2(xv.x - yv.x, xv.y - yv.y);
        const float2 ssv = make_float2(sv.x * sv.x, sv.y * sv.y);
        const float2 ddv = make_float2(dv.x * dv.x, dv.y * dv.y);
#pragma unroll
        for (int j = 0; j < 4; ++j) {
            const int t = k - j;               // compile-time
            if (t >= 0 && t <= 10) {
                const float g = win.g[t];
                acc[j][0].x += g * sv.x;   acc[j][0].y += g * sv.y;
                acc[j][1].x += g * dv.x;   acc[j][1].y += g * dv.y;
                acc[j][2].x += g * ssv.x;  acc[j][2].y += g * ssv.y;
                acc[j][3].x += g * ddv.x;  acc[j][3].y += g * ddv.y;
            }
        }
    }
#pragma unroll
    for (int j = 0; j < 4; ++j)
#pragma unroll
        for (int f = 0; f < 4; ++f)
            *(float2*)&hb[(j * 4 + f) * PSTR + pws] = acc[j][f];
}

template<bool CHK>
__device__ __forceinline__ float pair_body(const float* __restrict__ xp,
                                           const float* __restrict__ yp,
                                           int r0, int c0, int tid,
                                           float* __restrict__ hb,
                                           const GWin& win)
{
    const int pws = swzd(2 * tid);
    const int row = tid >> 6, l = tid & 63;
    int pb[6];
#pragma unroll
    for (int B = 0; B < 6; ++B) {        // hoisted h-read addresses (clamped)
        int blk = 2 * l - 2 + B;
        blk = blk < 0 ? 0 : (blk > 127 ? 127 : blk);
        pb[B] = 4 * swzd4(blk);
    }

    float2 xr[18], yr[18];
    float lsum = 0.f;

    // ================= band A: rows r0 .. r0+7 =================
#pragma unroll
    for (int i = 0; i < 14; ++i) {       // cold prologue (band A)
        xr[i] = ld2<CHK>(xp, r0 - 5 + i, c0);
        yr[i] = ld2<CHK>(yp, r0 - 5 + i, c0);
    }
    vconv4<0>(xr, yr, hb, pws, win);     // quad A0
    __syncthreads();

#pragma unroll
    for (int i = 14; i < 18; ++i) {      // prefetch A-q1 rows under hpass
        xr[i] = ld2<CHK>(xp, r0 - 5 + i, c0);
        yr[i] = ld2<CHK>(yp, r0 - 5 + i, c0);
    }
    lsum += hpass8(hb + row * 4 * PSTR, l, pb, win);
    __syncthreads();

    vconv4<4>(xr, yr, hb, pws, win);     // quad A1 (last read of band-A rows)
    __syncthreads();

    // issue band B prologue NOW (same regs; WAR safe by in-order issue);
    // the 28 loads fly under hpass(A-q1) below.
    const int r1 = r0 + R_PER_BAND;
#pragma unroll
    for (int i = 0; i < 14; ++i) {
        xr[i] = ld2<CHK>(xp, r1 - 5 + i, c0);
        yr[i] = ld2<CHK>(yp, r1 - 5 + i, c0);
    }
    lsum += hpass8(hb + row * 4 * PSTR, l, pb, win);
    __syncthreads();                      // hbuf free for band B

    // ================= band B: rows r1 .. r1+7 =================
    vconv4<0>(xr, yr, hb, pws, win);     // quad B0
    __syncthreads();

#pragma unroll
    for (int i = 14; i < 18; ++i) {      // prefetch B-q1 rows under hpass
        xr[i] = ld2<CHK>(xp, r1 - 5 + i, c0);
        yr[i] = ld2<CHK>(yp, r1 - 5 + i, c0);
    }
    lsum += hpass8(hb + row * 4 * PSTR, l, pb, win);
    __syncthreads();

    vconv4<4>(xr, yr, hb, pws, win);     // quad B1
    __syncthreads();

    lsum += hpass8(hb + row * 4 * PSTR, l, pb, win);
    return lsum;
}

__global__ __launch_bounds__(256)
void ssim_2b_kernel(const float* __restrict__ x,
                    const float* __restrict__ y,
                    double* __restrict__ accum,
                    GWin win)
{
    __shared__ __align__(16) float hbuf[4 * 4 * PSTR];   // exactly 32768 B

    const int tid = threadIdx.x;
    // XCD-aware swizzle: consecutive logical band-pairs share one XCD's L2.
    const int bid = blockIdx.x;
    const int L   = (bid & 7) * (NBLK / 8) + (bid >> 3);
    const int bp    = L & (BPAIRS - 1);
    const int plane = L >> 5;
    const int r0    = bp * 16;
    const int c0    = tid * 2;

    const float* __restrict__ xp = x + (size_t)plane * (IMG_H * IMG_W);
    const float* __restrict__ yp = y + (size_t)plane * (IMG_H * IMG_W);

    float lsum;
    if (bp >= 1 && bp <= BPAIRS - 2)     // rows touched: r0-5 .. r0+20
        lsum = pair_body<false>(xp, yp, r0, c0, tid, hbuf, win);
    else
        lsum = pair_body<true>(xp, yp, r0, c0, tid, hbuf, win);

    // wave reduction, then one scattered global atomic per wave (no LDS)
#pragma unroll
    for (int off = 32; off; off >>= 1) lsum += __shfl_down(lsum, off);
    if ((tid & 63) == 0) {
        const int wid = L * 4 + (tid >> 6);
        atomicAdd(&accum[(wid & (NSLOT - 1)) * 8], (double)lsum);  // 64B stride
    }
}

// Parallel finalize: 64 lanes load the slots concurrently, f64 butterfly.
__global__ __launch_bounds__(64)
void ssim_finalize_kernel(const double* __restrict__ accum,
                          float* __restrict__ out)
{
    const int l = threadIdx.x;
    double s = accum[l * 8];
#pragma unroll
    for (int off = 32; off; off >>= 1) s += __shfl_down(s, off);
    if (l == 0) out[0] = (float)(s / (double)TOTAL_PIX);
}

extern "C" void kernel_launch(void* const* d_in, const int* in_sizes, int n_in,
                              void* d_out, int out_size, void* d_ws, size_t ws_size,
                              hipStream_t stream) {
    const float* x = (const float*)d_in[0];
    const float* y = (const float*)d_in[1];
    float* out = (float*)d_out;
    double* accum = (double*)d_ws;

    GWin win;
    {
        double g[11], s = 0.0;
        for (int i = 0; i < 11; ++i) {
            double d = (double)i - 5.0;
            g[i] = std::exp(-(d * d) / (2.0 * 1.5 * 1.5));
            s += g[i];
        }
        for (int i = 0; i < 11; ++i) win.g[i] = (float)(g[i] / s);
    }

    (void)hipMemsetAsync(d_ws, 0, NSLOT * 8 * sizeof(double), stream);

    ssim_2b_kernel<<<NBLK, 256, 0, stream>>>(x, y, accum, win);
    ssim_finalize_kernel<<<1, 64, 0, stream>>>(accum, out);
}

// Round 26
// 59.854 us; speedup vs baseline: 1.3307x; 1.3307x over previous
//
#include <hip/hip_runtime.h>
#include <cmath>

// x,y: (16,3,512,512) f32. Fused separable-Gaussian SSIM, scalar mean output.
// CHAMPION (R22/R24, 60.1-60.3us): sum/diff 4-field basis {s=x+y, d=x-y,
// s^2, d^2} (SSIM needs only mu_x,mu_y,sig_xy,sig_x+sig_y -> 20% less conv
// work), 32KB LDS (5 blocks/CU), cross-quad row sharing + prefetch under
// h-pass, XOR bank swizzle, XCD block swizzle, rcp div, parallel finalize.
//
// Falsified alternatives (counter evidence): occupancy+ (R15/R18 no effect),
// phase-merge (R19 VGPR 172), b64 window (R20 worse banks), 4-quad window
// (R23 VGPR 172), 2-band prologue reuse (R25 VGPR 168), pk-f32 (R16 rate-
// neutral), wave-private shuffle design (R12 L2 blowup).
constexpr int IMG_H = 512;
constexpr int IMG_W = 512;
constexpr int PLANES = 48;
constexpr int R_OUT = 8;                 // output rows per block (2 quads)
constexpr int BANDS = IMG_H / R_OUT;     // 64
constexpr int PSTR = 512;                // field-row dwords; col c at dword c
constexpr int NSLOT = 64;                // global accumulator slots (64B apart)
constexpr int NBLK = PLANES * BANDS;     // 3072 (divisible by 8 XCDs)
constexpr long long TOTAL_PIX = (long long)PLANES * IMG_H * IMG_W;

struct GWin { float g[11]; };

// XOR bank swizzle on within-field-row dword offset (bits 2..4 ^= bits 5..7).
__device__ __forceinline__ int swzd(int d) { return d ^ (((d >> 5) & 7) << 2); }
__device__ __forceinline__ int swzd4(int b) { return b ^ ((b >> 3) & 7); }

template<bool CHK>
__device__ __forceinline__ float2 ld2(const float* __restrict__ base, int gr, int c0) {
    if (CHK && (unsigned)gr >= (unsigned)IMG_H) return make_float2(0.f, 0.f);
    return *(const float2*)(base + (size_t)gr * IMG_W + c0);
}

// horizontal 11-tap conv + SSIM over one LDS row (4 fields), 8 cols per lane.
__device__ __forceinline__ float hpass8(const float* __restrict__ fr0,
                                        int l, const int (&pb)[6],
                                        const GWin& win) {
    float m[4][8];
#pragma unroll
    for (int f = 0; f < 4; ++f) {
        const float* fr = fr0 + f * PSTR;
        float w24[24];
#pragma unroll
        for (int B = 0; B < 6; ++B) {
            const float4 v = *(const float4*)&fr[pb[B]];
            w24[4 * B + 0] = v.x;  w24[4 * B + 1] = v.y;
            w24[4 * B + 2] = v.z;  w24[4 * B + 3] = v.w;
        }
        if (l == 0)  { w24[3] = w24[4] = w24[5] = w24[6] = w24[7] = 0.f; }
        if (l == 63) { w24[16] = w24[17] = w24[18] = w24[19] = w24[20] = 0.f; }
        // output col c = 8l+j: window cols c-5..c+5 -> w24[j+3+k]
#pragma unroll
        for (int j = 0; j < 8; ++j) {
            float s = 0.f;
#pragma unroll
            for (int k = 0; k < 11; ++k) s += win.g[k] * w24[j + 3 + k];
            m[f][j] = s;
        }
    }
    float ls = 0.f;
#pragma unroll
    for (int u = 0; u < 8; ++u) {
        const float sb  = m[0][u];        // conv(x+y)
        const float db  = m[1][u];        // conv(x-y)
        const float css = m[2][u];        // conv((x+y)^2)
        const float cdd = m[3][u];        // conv((x-y)^2)
        const float A = sb * sb;
        const float B = db * db;
        const float C1 = 0.01f * 0.01f;
        const float C2 = 0.03f * 0.03f;
        const float n1 = 0.5f * (A - B) + C1;
        const float n2 = 0.5f * ((css - cdd) - (A - B)) + C2;
        const float d1 = 0.5f * (A + B) + C1;
        const float d2 = 0.5f * ((css + cdd) - (A + B)) + C2;
        ls += (n1 * n2) * __builtin_amdgcn_rcpf(d1 * d2 + 1e-8f);  // ~1 ulp
    }
    return ls;
}

// v-conv of 4 rows x 4 fields {s,d,ss,dd} from 14 resident register rows
template<int I0>
__device__ __forceinline__ void vconv4(const float2 (&xr)[18], const float2 (&yr)[18],
                                       float* __restrict__ hb, int pws,
                                       const GWin& win) {
    float2 acc[4][4];
#pragma unroll
    for (int j = 0; j < 4; ++j)
#pragma unroll
        for (int f = 0; f < 4; ++f) acc[j][f] = make_float2(0.f, 0.f);
#pragma unroll
    for (int k = 0; k < 14; ++k) {
        const float2 xv = xr[I0 + k], yv = yr[I0 + k];
        const float2 sv = make_float2(xv.x + yv.x, xv.y + yv.y);
        const float2 dv = make_float2(xv.x - yv.x, xv.y - yv.y);
        const float2 ssv = make_float2(sv.x * sv.x, sv.y * sv.y);
        const float2 ddv = make_float2(dv.x * dv.x, dv.y * dv.y);
#pragma unroll
        for (int j = 0; j < 4; ++j) {
            const int t = k - j;               // compile-time
            if (t >= 0 && t <= 10) {
                const float g = win.g[t];
                acc[j][0].x += g * sv.x;   acc[j][0].y += g * sv.y;
                acc[j][1].x += g * dv.x;   acc[j][1].y += g * dv.y;
                acc[j][2].x += g * ssv.x;  acc[j][2].y += g * ssv.y;
                acc[j][3].x += g * ddv.x;  acc[j][3].y += g * ddv.y;
            }
        }
    }
#pragma unroll
    for (int j = 0; j < 4; ++j)
#pragma unroll
        for (int f = 0; f < 4; ++f)
            *(float2*)&hb[(j * 4 + f) * PSTR + pws] = acc[j][f];
}

template<bool CHK>
__device__ __forceinline__ float band_body(const float* __restrict__ xp,
                                           const float* __restrict__ yp,
                                           int r0, int c0, int tid,
                                           float* __restrict__ hb,
                                           const GWin& win)
{
    const int pws = swzd(2 * tid);
    const int row = tid >> 6, l = tid & 63;
    int pb[6];
#pragma unroll
    for (int B = 0; B < 6; ++B) {        // hoisted h-read addresses (clamped)
        int blk = 2 * l - 2 + B;
        blk = blk < 0 ? 0 : (blk > 127 ? 127 : blk);
        pb[B] = 4 * swzd4(blk);
    }

    // rows i=0..17 <-> image rows r0-5+i. Load 0..13 now (quad 0).
    float2 xr[18], yr[18];
#pragma unroll
    for (int i = 0; i < 14; ++i) {
        xr[i] = ld2<CHK>(xp, r0 - 5 + i, c0);
        yr[i] = ld2<CHK>(yp, r0 - 5 + i, c0);
    }

    // quad 0: rows r0..r0+3 from xr[0..13]
    vconv4<0>(xr, yr, hb, pws, win);
    __syncthreads();

    // prefetch quad-1-only rows (i=14..17) under the q0 h-pass
#pragma unroll
    for (int i = 14; i < 18; ++i) {
        xr[i] = ld2<CHK>(xp, r0 - 5 + i, c0);
        yr[i] = ld2<CHK>(yp, r0 - 5 + i, c0);
    }

    float lsum = hpass8(hb + row * 4 * PSTR, l, pb, win);
    __syncthreads();                      // protect hbuf before q1 writes

    // quad 1: rows r0+4..r0+7 from xr[4..17]
    vconv4<4>(xr, yr, hb, pws, win);
    __syncthreads();

    lsum += hpass8(hb + row * 4 * PSTR, l, pb, win);
    return lsum;
}

__global__ __launch_bounds__(256)
void ssim_sd_kernel(const float* __restrict__ x,
                    const float* __restrict__ y,
                    double* __restrict__ accum,
                    GWin win)
{
    __shared__ __align__(16) float hbuf[4 * 4 * PSTR];   // exactly 32768 B

    const int tid = threadIdx.x;
    // XCD-aware swizzle: consecutive logical bands share one XCD's L2.
    const int bid = blockIdx.x;
    const int L   = (bid & 7) * (NBLK / 8) + (bid >> 3);
    const int band  = L & (BANDS - 1);
    const int plane = L >> 6;
    const int r0    = band * R_OUT;
    const int c0    = tid * 2;

    const float* __restrict__ xp = x + (size_t)plane * (IMG_H * IMG_W);
    const float* __restrict__ yp = y + (size_t)plane * (IMG_H * IMG_W);

    float lsum;
    if (band >= 1 && band <= BANDS - 2)
        lsum = band_body<false>(xp, yp, r0, c0, tid, hbuf, win);
    else
        lsum = band_body<true>(xp, yp, r0, c0, tid, hbuf, win);

    // wave reduction, then one scattered global atomic per wave (no LDS)
#pragma unroll
    for (int off = 32; off; off >>= 1) lsum += __shfl_down(lsum, off);
    if ((tid & 63) == 0) {
        const int wid = L * 4 + (tid >> 6);
        atomicAdd(&accum[(wid & (NSLOT - 1)) * 8], (double)lsum);  // 64B stride
    }
}

// Parallel finalize: 64 lanes load the slots concurrently, f64 butterfly.
__global__ __launch_bounds__(64)
void ssim_finalize_kernel(const double* __restrict__ accum,
                          float* __restrict__ out)
{
    const int l = threadIdx.x;
    double s = accum[l * 8];
#pragma unroll
    for (int off = 32; off; off >>= 1) s += __shfl_down(s, off);
    if (l == 0) out[0] = (float)(s / (double)TOTAL_PIX);
}

extern "C" void kernel_launch(void* const* d_in, const int* in_sizes, int n_in,
                              void* d_out, int out_size, void* d_ws, size_t ws_size,
                              hipStream_t stream) {
    const float* x = (const float*)d_in[0];
    const float* y = (const float*)d_in[1];
    float* out = (float*)d_out;
    double* accum = (double*)d_ws;

    GWin win;
    {
        double g[11], s = 0.0;
        for (int i = 0; i < 11; ++i) {
            double d = (double)i - 5.0;
            g[i] = std::exp(-(d * d) / (2.0 * 1.5 * 1.5));
            s += g[i];
        }
        for (int i = 0; i < 11; ++i) win.g[i] = (float)(g[i] / s);
    }

    (void)hipMemsetAsync(d_ws, 0, NSLOT * 8 * sizeof(double), stream);

    ssim_sd_kernel<<<NBLK, 256, 0, stream>>>(x, y, accum, win);
    ssim_finalize_kernel<<<1, 64, 0, stream>>>(accum, out);
}